// Round 4
// baseline (39619.476 us; speedup 1.0000x reference)
//
#include <hip/hip_runtime.h>
#include <cstdint>
#include <cstddef>

// SNN pipeline, round 13:
//  k1: unchanged from round 10.
//  k2: round-12 body, residency fixed. Diagnosis: dur x MfmaUtil == 1325 us
//      (the exact MFMA floor) in every round -> loss is coverage, and
//      __launch_bounds__(512,4) self-capped the CU at 2 blocks (41% occ).
//      Now: depth-2 LDS pipeline (32 KB total) + __launch_bounds__(512,8)
//      -> 4 blocks/CU co-resident, 4 independent barrier groups per CU; the
//      per-tile vmcnt(0) drain of one block hides under the other blocks'
//      MFMA clusters. Staging via global_load_lds width-16 (fragment-linear
//      slot = base+lane*16), STAGE(t+1) at top (readers of buf^1 passed the
//      previous end-of-tile barrier -> race-free), setprio(1) around MFMA.
//      Numerics BIT-IDENTICAL to round 9: same MFMA sequence/fragments, same
//      LIF-2 chains + thalf handoff, same po layout.
//  k3: unchanged.
// ws: w2d 4MiB @0 | s1bits 128MiB @16MiB | po 80MiB @160MiB

typedef _Float16 f16;
typedef _Float16 f16x8 __attribute__((ext_vector_type(8)));
typedef float f32x4 __attribute__((ext_vector_type(4)));
typedef int i32x4 __attribute__((ext_vector_type(4)));
typedef unsigned int u32;

#define MFMA16(A, B, C) __builtin_amdgcn_mfma_f32_16x16x32_f16(A, B, C, 0, 0, 0)

static constexpr int BSZ = 65536;
static constexpr int IN = 512;
static constexpr int H = 1024;

__device__ __forceinline__ void gl_lds16(const void* g, void* l) {
    __builtin_amdgcn_global_load_lds(
        (const __attribute__((address_space(1))) u32*)g,
        (__attribute__((address_space(3))) u32*)l, 16, 0, 0);
}

// W2[k][j] fp32 -> w2d[plane][j][k] f16 Dekker limbs: plane0 = f16(w),
// plane1 = f16((w - hi) * 2^11).
__global__ void prep_dekker(const float* __restrict__ src, f16* __restrict__ dst) {
    int idx = blockIdx.x * 256 + threadIdx.x;
    int k = idx >> 10;
    int j = idx & 1023;
    float w = src[(size_t)k * 1024 + j];
    f16 hi = (f16)w;
    float lo = (w - (float)hi) * 2048.0f;
    size_t o = (size_t)j * 1024 + k;
    dst[o] = hi;
    dst[o + (size_t)H * H] = (f16)lo;
}

// k1: fp32 k-ordered FMA-chain GEMM (BLAS-replica) + fp32-replica LIF -> masks.
// tile 128 b-rows x 256 h-cols, 256 threads = 16 ht x 16 bt, thread = 8b x 16h.
__global__ __launch_bounds__(256, 2) void k1_chain(
    const float* __restrict__ x, const float* __restrict__ w1,
    const float* __restrict__ b1, unsigned short* __restrict__ s1b) {
    __shared__ float xs[32][132];   // [k][b]; stride 132: rows 16B-aligned, banks spread
    __shared__ float ws[32][256];   // [k][h]
    const int hblk = blockIdx.x;    // 4
    const int bblk = blockIdx.y;    // 512
    const int tid = threadIdx.x;
    const int ht = tid & 15, bt = tid >> 4;
    const int h0 = hblk * 256, b0 = bblk * 128;

    float acc[8][16] = {};

    float4 xv[4], wv[8];
#pragma unroll
    for (int i = 0; i < 4; ++i) {
        int idx = tid + 256 * i;            // 1024 f4: 128 rows x 8 segs
        int br = idx >> 3, ks = idx & 7;
        xv[i] = *(const float4*)&x[(size_t)(b0 + br) * IN + ks * 4];
    }
#pragma unroll
    for (int i = 0; i < 8; ++i) {
        int idx = tid + 256 * i;            // 2048 f4: 32 rows x 64 segs
        int kr = idx >> 6, c4 = idx & 63;
        wv[i] = *(const float4*)&w1[(size_t)kr * H + h0 + c4 * 4];
    }

    for (int kc = 0; kc < 512; kc += 32) {
        __syncthreads();                    // prev compute's LDS reads done
#pragma unroll
        for (int i = 0; i < 4; ++i) {
            int idx = tid + 256 * i;
            int br = idx >> 3, ks = idx & 7;
            xs[ks * 4 + 0][br] = xv[i].x;
            xs[ks * 4 + 1][br] = xv[i].y;
            xs[ks * 4 + 2][br] = xv[i].z;
            xs[ks * 4 + 3][br] = xv[i].w;
        }
#pragma unroll
        for (int i = 0; i < 8; ++i) {
            int idx = tid + 256 * i;
            int kr = idx >> 6, c4 = idx & 63;
            *(float4*)&ws[kr][c4 * 4] = wv[i];
        }
        __syncthreads();
        int kn = (kc + 32) & 511;           // wraps to 0 on last chunk (dummy)
#pragma unroll
        for (int i = 0; i < 4; ++i) {
            int idx = tid + 256 * i;
            int br = idx >> 3, ks = idx & 7;
            xv[i] = *(const float4*)&x[(size_t)(b0 + br) * IN + kn + ks * 4];
        }
#pragma unroll
        for (int i = 0; i < 8; ++i) {
            int idx = tid + 256 * i;
            int kr = idx >> 6, c4 = idx & 63;
            wv[i] = *(const float4*)&w1[(size_t)(kn + kr) * H + h0 + c4 * 4];
        }
#pragma unroll 2
        for (int k = 0; k < 32; ++k) {
            float xr[8];
            *(float4*)&xr[0] = *(const float4*)&xs[k][bt * 8];
            *(float4*)&xr[4] = *(const float4*)&xs[k][bt * 8 + 4];
            float wr[16];
#pragma unroll
            for (int g = 0; g < 4; ++g)
                *(float4*)&wr[g * 4] = *(const float4*)&ws[k][ht * 4 + 64 * g];
#pragma unroll
            for (int i = 0; i < 8; ++i)
#pragma unroll
                for (int j = 0; j < 16; ++j)
                    acc[i][j] = fmaf(xr[i], wr[j], acc[i][j]);  // strict k-order chain
        }
    }

    float b1v[16];
#pragma unroll
    for (int g = 0; g < 4; ++g)
#pragma unroll
        for (int m = 0; m < 4; ++m)
            b1v[g * 4 + m] = b1[h0 + g * 64 + ht * 4 + m];
#pragma unroll
    for (int i = 0; i < 8; ++i) {
        unsigned short outb[16];
#pragma unroll
        for (int j = 0; j < 16; ++j) {
            float c = __fadd_rn(acc[i][j], b1v[j]);
            float m = 0.0f;
            unsigned bits = 0u;
#pragma unroll
            for (int t = 0; t < 10; ++t) {
                float rst = (m > 1.0f) ? 1.0f : 0.0f;
                m = __fmul_rn(0.9f, m);
                m = __fadd_rn(m, c);
                m = __fsub_rn(m, rst);
                if (m > 1.0f) bits |= (1u << t);
            }
            outb[j] = (unsigned short)bits;
        }
        size_t row = (size_t)(b0 + bt * 8 + i);
#pragma unroll
        for (int g = 0; g < 4; ++g)
            *(int2*)&s1b[row * H + h0 + g * 64 + ht * 4] = ((const int2*)outb)[g];
    }
}

// k2: spike GEMM. Block = 64 rows x 32 cols, 512 threads = 8 waves:
// wave = (strip = w&3) x (thalf = w>>2). Fragment-linear LDS, BK=64,
// depth-2 global_load_lds pipeline, 4 blocks/CU via launch_bounds(512,8).
__global__ __launch_bounds__(512, 8) void k2_spikes_gemm(
    const unsigned short* __restrict__ s1bits, const f16* __restrict__ w2d,
    const float* __restrict__ b2, const float* __restrict__ wo,
    float* __restrict__ po) {
    // [2 bufs][kch][role][slot] fragment-linear; m2x aliases buf0's A region
    __shared__ __align__(16) char ldsraw[32768];
    i32x4 (*AL)[2][4][64]    = (i32x4 (*)[2][4][64])ldsraw;              // 2x8KB
    i32x4 (*BL)[2][2][2][64] = (i32x4 (*)[2][2][2][64])(ldsraw + 16384); // 2x8KB
    float (*m2x)[64][8]      = (float (*)[64][8])ldsraw;                 // 8KB alias

    const int jblk = blockIdx.x, bblk = blockIdx.y;
    const int tid = threadIdx.x;
    const int lane = tid & 63, wave = tid >> 6;
    const int strip = wave & 3, thalf = wave >> 2;
    const int l15 = lane & 15, loct = lane >> 4;
    const int t0 = thalf * 5;

    // staging roles: waves 0-3 stage A strip w (2 gloads/tile: kch0, kch1);
    // waves 4-7 stage B (plane bp, colfrag bcf). slot index == lane, so the
    // LDS dest is wave-uniform base + lane*16 == global_load_lds semantics,
    // and the per-lane global source matches round 9's fragment placement.
    const bool stB = (wave >= 4);
    const int bp = (wave >> 1) & 1, bcf = wave & 1;
    const unsigned short* gA =
        s1bits + (size_t)(bblk * 64 + strip * 16 + l15) * 1024 + loct * 8;
    const f16* gB = w2d + (size_t)bp * H * H
                  + (size_t)(jblk * 32 + bcf * 16 + l15) * 1024 + loct * 8;

    f32x4 acc[5][2][2] = {};   // [tt][plane][colfrag] = 80 acc regs

    typedef union { i32x4 i; unsigned long long u[2]; f16x8 h; } U;

#define STAGE(t_)                                                        \
    do {                                                                 \
        int bi_ = (t_) & 1;                                              \
        int kk_ = ((t_) * 64) & 1023;                                    \
        if (stB) {                                                       \
            gl_lds16(gB + kk_,      &BL[bi_][0][bp][bcf][0]);            \
            gl_lds16(gB + kk_ + 32, &BL[bi_][1][bp][bcf][0]);            \
        } else {                                                         \
            gl_lds16(gA + kk_,      &AL[bi_][0][strip][0]);              \
            gl_lds16(gA + kk_ + 32, &AL[bi_][1][strip][0]);              \
        }                                                                \
    } while (0)

    // prologue: stage tile 0, release it
    STAGE(0);
    asm volatile("s_waitcnt vmcnt(0)" ::: "memory");
    __builtin_amdgcn_s_barrier();

    for (int t = 0; t < 16; ++t) {
        const int bi = t & 1;
        // stage next tile into buf^1: its readers passed the previous
        // end-of-tile barrier, so the async DMA writes are race-free.
        STAGE(t + 1);   // t=15 wraps to kk=0 (dummy; drained before epilogue)
#pragma unroll
        for (int kch = 0; kch < 2; ++kch) {
            U m;
            m.i = AL[bi][kch][strip][lane];
            f16x8 bf[2][2];
#pragma unroll
            for (int p = 0; p < 2; ++p)
#pragma unroll
                for (int cf = 0; cf < 2; ++cf) {
                    U b; b.i = BL[bi][kch][p][cf][lane];
                    bf[p][cf] = b.h;
                }
            __builtin_amdgcn_s_setprio(1);
#pragma unroll
            for (int tt = 0; tt < 5; ++tt) {
                const int sh = 10 - (t0 + tt);
                U r;
                r.u[0] = (m.u[0] << sh) & 0x0400040004000400ULL;
                r.u[1] = (m.u[1] << sh) & 0x0400040004000400ULL;
                acc[tt][0][0] = MFMA16(r.h, bf[0][0], acc[tt][0][0]);
                acc[tt][0][1] = MFMA16(r.h, bf[0][1], acc[tt][0][1]);
                acc[tt][1][0] = MFMA16(r.h, bf[1][0], acc[tt][1][0]);
                acc[tt][1][1] = MFMA16(r.h, bf[1][1], acc[tt][1][1]);
            }
            __builtin_amdgcn_s_setprio(0);
        }
        // drain this tile's prefetch DMA, then release buf^1 to all waves.
        // With 4 blocks/CU the drain hides under other blocks' MFMA.
        asm volatile("s_waitcnt vmcnt(0)" ::: "memory");
        __builtin_amdgcn_s_barrier();
    }
#undef STAGE

    // epilogue: Dekker combine (unpack scale folded in: 16384, 8),
    // fp32-replica LIF-2 split across t-halves with LDS m2 handoff.
    // m2x aliases buf0-A: all DMA (incl. dummy tail) drained by the final
    // vmcnt(0) before the last barrier; no DMA in flight here.
    int col0 = jblk * 32 + l15;
    float b2v0 = b2[col0], b2v1 = b2[col0 + 16];
    double wov0 = (double)wo[col0], wov1 = (double)wo[col0 + 16];
    int rowb = bblk * 64 + strip * 16 + loct * 4;
    float m2a[4] = {0.0f, 0.0f, 0.0f, 0.0f};
    float m2b[4] = {0.0f, 0.0f, 0.0f, 0.0f};

    if (thalf == 0) {
#pragma unroll
        for (int tt = 0; tt < 5; ++tt) {
#pragma unroll
            for (int r = 0; r < 4; ++r) {
                float i0 = (float)((double)acc[tt][0][0][r] * 16384.0 + (double)acc[tt][1][0][r] * 8.0);
                i0 = __fadd_rn(i0, b2v0);
                float rst0 = (m2a[r] > 1.0f) ? 1.0f : 0.0f;
                m2a[r] = __fmul_rn(0.9f, m2a[r]);
                m2a[r] = __fadd_rn(m2a[r], i0);
                m2a[r] = __fsub_rn(m2a[r], rst0);
                float i1 = (float)((double)acc[tt][0][1][r] * 16384.0 + (double)acc[tt][1][1][r] * 8.0);
                i1 = __fadd_rn(i1, b2v1);
                float rst1 = (m2b[r] > 1.0f) ? 1.0f : 0.0f;
                m2b[r] = __fmul_rn(0.9f, m2b[r]);
                m2b[r] = __fadd_rn(m2b[r], i1);
                m2b[r] = __fsub_rn(m2b[r], rst1);
                double pv = ((m2a[r] > 1.0f) ? wov0 : 0.0) + ((m2b[r] > 1.0f) ? wov1 : 0.0);
                pv += __shfl_xor(pv, 1);
                pv += __shfl_xor(pv, 2);
                pv += __shfl_xor(pv, 4);
                pv += __shfl_xor(pv, 8);
                if (l15 == r)
                    po[(size_t)(tt * 32 + jblk) * BSZ + rowb + r] = (float)pv;
            }
        }
#pragma unroll
        for (int r = 0; r < 4; ++r) {
            m2x[strip][lane][r] = m2a[r];
            m2x[strip][lane][4 + r] = m2b[r];
        }
    }
    __syncthreads();
    if (thalf == 1) {
#pragma unroll
        for (int r = 0; r < 4; ++r) {
            m2a[r] = m2x[strip][lane][r];
            m2b[r] = m2x[strip][lane][4 + r];
        }
#pragma unroll
        for (int tt = 0; tt < 5; ++tt) {
#pragma unroll
            for (int r = 0; r < 4; ++r) {
                float i0 = (float)((double)acc[tt][0][0][r] * 16384.0 + (double)acc[tt][1][0][r] * 8.0);
                i0 = __fadd_rn(i0, b2v0);
                float rst0 = (m2a[r] > 1.0f) ? 1.0f : 0.0f;
                m2a[r] = __fmul_rn(0.9f, m2a[r]);
                m2a[r] = __fadd_rn(m2a[r], i0);
                m2a[r] = __fsub_rn(m2a[r], rst0);
                float i1 = (float)((double)acc[tt][0][1][r] * 16384.0 + (double)acc[tt][1][1][r] * 8.0);
                i1 = __fadd_rn(i1, b2v1);
                float rst1 = (m2b[r] > 1.0f) ? 1.0f : 0.0f;
                m2b[r] = __fmul_rn(0.9f, m2b[r]);
                m2b[r] = __fadd_rn(m2b[r], i1);
                m2b[r] = __fsub_rn(m2b[r], rst1);
                double pv = ((m2a[r] > 1.0f) ? wov0 : 0.0) + ((m2b[r] > 1.0f) ? wov1 : 0.0);
                pv += __shfl_xor(pv, 1);
                pv += __shfl_xor(pv, 2);
                pv += __shfl_xor(pv, 4);
                pv += __shfl_xor(pv, 8);
                if (l15 == r)
                    po[(size_t)((5 + tt) * 32 + jblk) * BSZ + rowb + r] = (float)pv;
            }
        }
    }
}

// k3: sum 32 partials (ascending j-blocks), fp32-replica LIF-out, mean.
__global__ void k3_out(const float* __restrict__ po, const float* __restrict__ bo,
                       float* __restrict__ out) {
    int b = blockIdx.x * 256 + threadIdx.x;
    float mo = 0.0f, s = 0.0f;
    float bov = bo[0];
    for (int t = 0; t < 10; ++t) {
        float inp = 0.0f;
#pragma unroll
        for (int jb = 0; jb < 32; ++jb) inp += po[(size_t)(t * 32 + jb) * BSZ + b];
        inp = __fadd_rn(inp, bov);
        float rst = (mo > 1.0f) ? 1.0f : 0.0f;
        mo = __fmul_rn(0.9f, mo);
        mo = __fadd_rn(mo, inp);
        mo = __fsub_rn(mo, rst);
        s += mo;
    }
    out[b] = s / 10.0f;
}

extern "C" void kernel_launch(void* const* d_in, const int* in_sizes, int n_in,
                              void* d_out, int out_size, void* d_ws, size_t ws_size,
                              hipStream_t stream) {
    (void)in_sizes; (void)n_in; (void)out_size; (void)ws_size;
    const float* x  = (const float*)d_in[0];
    const float* W1 = (const float*)d_in[1];
    const float* b1 = (const float*)d_in[2];
    const float* W2 = (const float*)d_in[3];
    const float* b2 = (const float*)d_in[4];
    const float* Wo = (const float*)d_in[5];
    const float* bo = (const float*)d_in[6];
    float* out = (float*)d_out;

    char* ws = (char*)d_ws;
    f16* w2d = (f16*)ws;                                                   // 4 MiB @ 0
    unsigned short* s1bits = (unsigned short*)(ws + ((size_t)16 << 20));   // 128 MiB
    float* po = (float*)(ws + ((size_t)160 << 20));                        // 80 MiB

    prep_dekker<<<dim3((H * H) / 256), 256, 0, stream>>>(W2, w2d);
    k1_chain<<<dim3(4, BSZ / 128), 256, 0, stream>>>(x, W1, b1, s1bits);
    k2_spikes_gemm<<<dim3(H / 32, BSZ / 64), 512, 0, stream>>>(s1bits, w2d, b2, Wo, po);
    k3_out<<<dim3(BSZ / 256), 256, 0, stream>>>(po, bo, out);
}

// Round 5
// 3539.766 us; speedup vs baseline: 11.1927x; 11.1927x over previous
//
#include <hip/hip_runtime.h>
#include <cstdint>
#include <cstddef>

// SNN pipeline, round 14:
//  k1: unchanged from round 10.
//  k2: cf-split wave decomposition. Diagnosis across r9-r13: dur x MfmaUtil ==
//      1325 us (MFMA floor) always; serialized LDS+MFMA model predicts the
//      measured 53-57% exactly (2328 vs 1630 cyc/CU/tile). Fix the LDS term:
//      wave = (strip, colfrag), owns ALL 10 timesteps of its 16 cols ->
//      per kch reads 1 A + 2 B b128 (was 1+4); per-CU LDS 1630->~1050 cyc.
//      acc[10][2] = 80 regs (same). No thalf handoff (m2x gone; its 3.1M bank
//      conflicts too). Cross-wave Wo partial: f64 partials to LDS (aliased
//      over dead staging bufs), one barrier, coalesced 640-float po write.
//      Depth-2 global_load_lds pipeline, vmcnt(0)+raw barrier per tile,
//      setprio around MFMA, __launch_bounds__(512,4) (r13's (512,8) spilled
//      acc to scratch: 39.6ms. NEVER force 8 waves/EU with 80-reg acc).
//      MFMA sequence/fragments/shifts bit-identical to round 9.
//  k3: unchanged.
// ws: w2d 4MiB @0 | s1bits 128MiB @16MiB | po 80MiB @160MiB

typedef _Float16 f16;
typedef _Float16 f16x8 __attribute__((ext_vector_type(8)));
typedef float f32x4 __attribute__((ext_vector_type(4)));
typedef int i32x4 __attribute__((ext_vector_type(4)));
typedef unsigned int u32;

#define MFMA16(A, B, C) __builtin_amdgcn_mfma_f32_16x16x32_f16(A, B, C, 0, 0, 0)

static constexpr int BSZ = 65536;
static constexpr int IN = 512;
static constexpr int H = 1024;

__device__ __forceinline__ void gl_lds16(const void* g, void* l) {
    __builtin_amdgcn_global_load_lds(
        (const __attribute__((address_space(1))) u32*)g,
        (__attribute__((address_space(3))) u32*)l, 16, 0, 0);
}

// W2[k][j] fp32 -> w2d[plane][j][k] f16 Dekker limbs: plane0 = f16(w),
// plane1 = f16((w - hi) * 2^11).
__global__ void prep_dekker(const float* __restrict__ src, f16* __restrict__ dst) {
    int idx = blockIdx.x * 256 + threadIdx.x;
    int k = idx >> 10;
    int j = idx & 1023;
    float w = src[(size_t)k * 1024 + j];
    f16 hi = (f16)w;
    float lo = (w - (float)hi) * 2048.0f;
    size_t o = (size_t)j * 1024 + k;
    dst[o] = hi;
    dst[o + (size_t)H * H] = (f16)lo;
}

// k1: fp32 k-ordered FMA-chain GEMM (BLAS-replica) + fp32-replica LIF -> masks.
// tile 128 b-rows x 256 h-cols, 256 threads = 16 ht x 16 bt, thread = 8b x 16h.
__global__ __launch_bounds__(256, 2) void k1_chain(
    const float* __restrict__ x, const float* __restrict__ w1,
    const float* __restrict__ b1, unsigned short* __restrict__ s1b) {
    __shared__ float xs[32][132];   // [k][b]; stride 132: rows 16B-aligned, banks spread
    __shared__ float ws[32][256];   // [k][h]
    const int hblk = blockIdx.x;    // 4
    const int bblk = blockIdx.y;    // 512
    const int tid = threadIdx.x;
    const int ht = tid & 15, bt = tid >> 4;
    const int h0 = hblk * 256, b0 = bblk * 128;

    float acc[8][16] = {};

    float4 xv[4], wv[8];
#pragma unroll
    for (int i = 0; i < 4; ++i) {
        int idx = tid + 256 * i;            // 1024 f4: 128 rows x 8 segs
        int br = idx >> 3, ks = idx & 7;
        xv[i] = *(const float4*)&x[(size_t)(b0 + br) * IN + ks * 4];
    }
#pragma unroll
    for (int i = 0; i < 8; ++i) {
        int idx = tid + 256 * i;            // 2048 f4: 32 rows x 64 segs
        int kr = idx >> 6, c4 = idx & 63;
        wv[i] = *(const float4*)&w1[(size_t)kr * H + h0 + c4 * 4];
    }

    for (int kc = 0; kc < 512; kc += 32) {
        __syncthreads();                    // prev compute's LDS reads done
#pragma unroll
        for (int i = 0; i < 4; ++i) {
            int idx = tid + 256 * i;
            int br = idx >> 3, ks = idx & 7;
            xs[ks * 4 + 0][br] = xv[i].x;
            xs[ks * 4 + 1][br] = xv[i].y;
            xs[ks * 4 + 2][br] = xv[i].z;
            xs[ks * 4 + 3][br] = xv[i].w;
        }
#pragma unroll
        for (int i = 0; i < 8; ++i) {
            int idx = tid + 256 * i;
            int kr = idx >> 6, c4 = idx & 63;
            *(float4*)&ws[kr][c4 * 4] = wv[i];
        }
        __syncthreads();
        int kn = (kc + 32) & 511;           // wraps to 0 on last chunk (dummy)
#pragma unroll
        for (int i = 0; i < 4; ++i) {
            int idx = tid + 256 * i;
            int br = idx >> 3, ks = idx & 7;
            xv[i] = *(const float4*)&x[(size_t)(b0 + br) * IN + kn + ks * 4];
        }
#pragma unroll
        for (int i = 0; i < 8; ++i) {
            int idx = tid + 256 * i;
            int kr = idx >> 6, c4 = idx & 63;
            wv[i] = *(const float4*)&w1[(size_t)(kn + kr) * H + h0 + c4 * 4];
        }
#pragma unroll 2
        for (int k = 0; k < 32; ++k) {
            float xr[8];
            *(float4*)&xr[0] = *(const float4*)&xs[k][bt * 8];
            *(float4*)&xr[4] = *(const float4*)&xs[k][bt * 8 + 4];
            float wr[16];
#pragma unroll
            for (int g = 0; g < 4; ++g)
                *(float4*)&wr[g * 4] = *(const float4*)&ws[k][ht * 4 + 64 * g];
#pragma unroll
            for (int i = 0; i < 8; ++i)
#pragma unroll
                for (int j = 0; j < 16; ++j)
                    acc[i][j] = fmaf(xr[i], wr[j], acc[i][j]);  // strict k-order chain
        }
    }

    float b1v[16];
#pragma unroll
    for (int g = 0; g < 4; ++g)
#pragma unroll
        for (int m = 0; m < 4; ++m)
            b1v[g * 4 + m] = b1[h0 + g * 64 + ht * 4 + m];
#pragma unroll
    for (int i = 0; i < 8; ++i) {
        unsigned short outb[16];
#pragma unroll
        for (int j = 0; j < 16; ++j) {
            float c = __fadd_rn(acc[i][j], b1v[j]);
            float m = 0.0f;
            unsigned bits = 0u;
#pragma unroll
            for (int t = 0; t < 10; ++t) {
                float rst = (m > 1.0f) ? 1.0f : 0.0f;
                m = __fmul_rn(0.9f, m);
                m = __fadd_rn(m, c);
                m = __fsub_rn(m, rst);
                if (m > 1.0f) bits |= (1u << t);
            }
            outb[j] = (unsigned short)bits;
        }
        size_t row = (size_t)(b0 + bt * 8 + i);
#pragma unroll
        for (int g = 0; g < 4; ++g)
            *(int2*)&s1b[row * H + h0 + g * 64 + ht * 4] = ((const int2*)outb)[g];
    }
}

// k2: spike GEMM. Block = 64 rows x 32 cols, 512 threads = 8 waves:
// wave = (strip = w&3) x (colfrag = w>>2); each wave owns all 10 timesteps of
// its 16 cols. Fragment-linear LDS, BK=64, depth-2 global_load_lds pipeline.
__global__ __launch_bounds__(512, 4) void k2_spikes_gemm(
    const unsigned short* __restrict__ s1bits, const f16* __restrict__ w2d,
    const float* __restrict__ b2, const float* __restrict__ wo,
    float* __restrict__ po) {
    // [2 bufs][kch][role][slot] fragment-linear; pvx aliases buf region
    __shared__ __align__(16) char ldsraw[32768];
    i32x4 (*AL)[2][4][64]    = (i32x4 (*)[2][4][64])ldsraw;              // 2x8KB
    i32x4 (*BL)[2][2][2][64] = (i32x4 (*)[2][2][2][64])(ldsraw + 16384); // 2x8KB
    double (*pvx)[10][4][16] = (double (*)[10][4][16])ldsraw;            // 10KB alias

    const int jblk = blockIdx.x, bblk = blockIdx.y;
    const int tid = threadIdx.x;
    const int lane = tid & 63, wave = tid >> 6;
    const int strip = wave & 3, cfw = wave >> 2;   // compute roles
    const int l15 = lane & 15, loct = lane >> 4;

    // staging roles (as r12/13): waves 0-3 stage A strips, waves 4-7 stage B
    // (plane bp, colfrag bcf). slot == lane -> LDS dest = base + lane*16,
    // exactly global_load_lds semantics; source matches fragment placement.
    const bool stB = (wave >= 4);
    const int bp = (wave >> 1) & 1, bcf = wave & 1;
    const unsigned short* gA =
        s1bits + (size_t)(bblk * 64 + strip * 16 + l15) * 1024 + loct * 8;
    const f16* gB = w2d + (size_t)bp * H * H
                  + (size_t)(jblk * 32 + bcf * 16 + l15) * 1024 + loct * 8;

    f32x4 acc[10][2] = {};   // [tt][plane] = 80 acc regs

    typedef union { i32x4 i; unsigned long long u[2]; f16x8 h; } U;

#define STAGE(t_)                                                        \
    do {                                                                 \
        int bi_ = (t_) & 1;                                              \
        int kk_ = ((t_) * 64) & 1023;                                    \
        if (stB) {                                                       \
            gl_lds16(gB + kk_,      &BL[bi_][0][bp][bcf][0]);            \
            gl_lds16(gB + kk_ + 32, &BL[bi_][1][bp][bcf][0]);            \
        } else {                                                         \
            gl_lds16(gA + kk_,      &AL[bi_][0][strip][0]);              \
            gl_lds16(gA + kk_ + 32, &AL[bi_][1][strip][0]);              \
        }                                                                \
    } while (0)

    // prologue: stage tile 0, release it
    STAGE(0);
    asm volatile("s_waitcnt vmcnt(0)" ::: "memory");
    __builtin_amdgcn_s_barrier();

    for (int t = 0; t < 16; ++t) {
        const int bi = t & 1;
        // stage next tile into buf^1: its readers passed the previous
        // end-of-tile barrier, so the async DMA writes are race-free.
        STAGE(t + 1);   // t=15 wraps to kk=0 (dummy; drained before epilogue)
#pragma unroll
        for (int kch = 0; kch < 2; ++kch) {
            U m;
            m.i = AL[bi][kch][strip][lane];
            U b0; b0.i = BL[bi][kch][0][cfw][lane];
            U b1; b1.i = BL[bi][kch][1][cfw][lane];
            f16x8 bf0 = b0.h, bf1 = b1.h;
            __builtin_amdgcn_s_setprio(1);
#pragma unroll
            for (int tt = 0; tt < 10; ++tt) {
                const int sh = 10 - tt;
                U r;
                r.u[0] = (m.u[0] << sh) & 0x0400040004000400ULL;
                r.u[1] = (m.u[1] << sh) & 0x0400040004000400ULL;
                acc[tt][0] = MFMA16(r.h, bf0, acc[tt][0]);
                acc[tt][1] = MFMA16(r.h, bf1, acc[tt][1]);
            }
            __builtin_amdgcn_s_setprio(0);
        }
        // drain this tile's prefetch DMA, then release buf^1 to all waves.
        asm volatile("s_waitcnt vmcnt(0)" ::: "memory");
        __builtin_amdgcn_s_barrier();
    }
#undef STAGE

    // epilogue: Dekker combine (scales 16384, 8 folded in), fp32-replica
    // LIF-2; every wave runs all 10 timesteps for its 16 cols. Per-wave f64
    // Wo partials -> pvx (aliased over dead staging LDS; all DMA incl. the
    // dummy tail was drained by the final vmcnt(0) before the last barrier),
    // one barrier, then coalesced po writes.
    int col0 = jblk * 32 + cfw * 16 + l15;
    float b2v = b2[col0];
    double wov = (double)wo[col0];
    float m2[4] = {0.0f, 0.0f, 0.0f, 0.0f};

#pragma unroll
    for (int tt = 0; tt < 10; ++tt) {
#pragma unroll
        for (int r = 0; r < 4; ++r) {
            float iv = (float)((double)acc[tt][0][r] * 16384.0 + (double)acc[tt][1][r] * 8.0);
            iv = __fadd_rn(iv, b2v);
            float rst = (m2[r] > 1.0f) ? 1.0f : 0.0f;
            m2[r] = __fmul_rn(0.9f, m2[r]);
            m2[r] = __fadd_rn(m2[r], iv);
            m2[r] = __fsub_rn(m2[r], rst);
            double pv = (m2[r] > 1.0f) ? wov : 0.0;
            pv += __shfl_xor(pv, 1);
            pv += __shfl_xor(pv, 2);
            pv += __shfl_xor(pv, 4);
            pv += __shfl_xor(pv, 8);
            if (l15 == r)
                pvx[cfw][tt][strip][loct * 4 + r] = pv;
        }
    }
    __syncthreads();
    // 640 outputs: idx = tt*64 + row(0..63); po rows are contiguous.
    for (int idx = tid; idx < 640; idx += 512) {
        int tt = idx >> 6, row = idx & 63;
        double v = pvx[0][tt][row >> 4][row & 15] + pvx[1][tt][row >> 4][row & 15];
        po[(size_t)(tt * 32 + jblk) * BSZ + bblk * 64 + row] = (float)v;
    }
}

// k3: sum 32 partials (ascending j-blocks), fp32-replica LIF-out, mean.
__global__ void k3_out(const float* __restrict__ po, const float* __restrict__ bo,
                       float* __restrict__ out) {
    int b = blockIdx.x * 256 + threadIdx.x;
    float mo = 0.0f, s = 0.0f;
    float bov = bo[0];
    for (int t = 0; t < 10; ++t) {
        float inp = 0.0f;
#pragma unroll
        for (int jb = 0; jb < 32; ++jb) inp += po[(size_t)(t * 32 + jb) * BSZ + b];
        inp = __fadd_rn(inp, bov);
        float rst = (mo > 1.0f) ? 1.0f : 0.0f;
        mo = __fmul_rn(0.9f, mo);
        mo = __fadd_rn(mo, inp);
        mo = __fsub_rn(mo, rst);
        s += mo;
    }
    out[b] = s / 10.0f;
}

extern "C" void kernel_launch(void* const* d_in, const int* in_sizes, int n_in,
                              void* d_out, int out_size, void* d_ws, size_t ws_size,
                              hipStream_t stream) {
    (void)in_sizes; (void)n_in; (void)out_size; (void)ws_size;
    const float* x  = (const float*)d_in[0];
    const float* W1 = (const float*)d_in[1];
    const float* b1 = (const float*)d_in[2];
    const float* W2 = (const float*)d_in[3];
    const float* b2 = (const float*)d_in[4];
    const float* Wo = (const float*)d_in[5];
    const float* bo = (const float*)d_in[6];
    float* out = (float*)d_out;

    char* ws = (char*)d_ws;
    f16* w2d = (f16*)ws;                                                   // 4 MiB @ 0
    unsigned short* s1bits = (unsigned short*)(ws + ((size_t)16 << 20));   // 128 MiB
    float* po = (float*)(ws + ((size_t)160 << 20));                        // 80 MiB

    prep_dekker<<<dim3((H * H) / 256), 256, 0, stream>>>(W2, w2d);
    k1_chain<<<dim3(4, BSZ / 128), 256, 0, stream>>>(x, W1, b1, s1bits);
    k2_spikes_gemm<<<dim3(H / 32, BSZ / 64), 512, 0, stream>>>(s1bits, w2d, b2, Wo, po);
    k3_out<<<dim3(BSZ / 256), 256, 0, stream>>>(po, bo, out);
}

// Round 7
// 3403.441 us; speedup vs baseline: 11.6410x; 1.0401x over previous
//
#include <hip/hip_runtime.h>
#include <cstdint>
#include <cstddef>

// SNN pipeline, round 16 (= round 15 resubmitted; bench infra failed, no data):
//  k1: unchanged from round 10.
//  k2: r14 cf-split loop UNCHANGED (LDS-lean, 0 bank conflicts). Epilogue
//      rebuilt: r14 PMC showed VALUBusy 67% > MfmaUtil 49% — the f64 shfl-tree
//      Wo-reduce (10 f64 ops + 8 ds_bpermute per (tt,r), x40/lane) was ~25% of
//      k2. Spikes are BINARY -> replace the reduce with __ballot: per (tt,r)
//      store a u16 col-spike-mask straight to ws (same 80 MiB as f32 partials;
//      u32 word = cfw0|cfw1<<16 per (jblk,tt,row)). f64 Dekker combine kept
//      (guards near-threshold spikes); all other f64 + all cross-lane gone.
//      LIF-2 chain ops bit-identical -> spike decisions bit-identical.
//  k3: mask->wo dot: per b-row 320 coalesced u32 loads, 32 predicated f32
//      adds each, ascending-column order (wo staged LDS->regs per 32-chunk),
//      then the unchanged LIF-out chain. ~35 us for ~600 us of k2 savings.
// ws: w2d 4MiB @0 | s1bits 128MiB @16MiB | po32 masks 80MiB @160MiB

typedef _Float16 f16;
typedef _Float16 f16x8 __attribute__((ext_vector_type(8)));
typedef float f32x4 __attribute__((ext_vector_type(4)));
typedef int i32x4 __attribute__((ext_vector_type(4)));
typedef unsigned int u32;

#define MFMA16(A, B, C) __builtin_amdgcn_mfma_f32_16x16x32_f16(A, B, C, 0, 0, 0)

static constexpr int BSZ = 65536;
static constexpr int IN = 512;
static constexpr int H = 1024;

__device__ __forceinline__ void gl_lds16(const void* g, void* l) {
    __builtin_amdgcn_global_load_lds(
        (const __attribute__((address_space(1))) u32*)g,
        (__attribute__((address_space(3))) u32*)l, 16, 0, 0);
}

// W2[k][j] fp32 -> w2d[plane][j][k] f16 Dekker limbs: plane0 = f16(w),
// plane1 = f16((w - hi) * 2^11).
__global__ void prep_dekker(const float* __restrict__ src, f16* __restrict__ dst) {
    int idx = blockIdx.x * 256 + threadIdx.x;
    int k = idx >> 10;
    int j = idx & 1023;
    float w = src[(size_t)k * 1024 + j];
    f16 hi = (f16)w;
    float lo = (w - (float)hi) * 2048.0f;
    size_t o = (size_t)j * 1024 + k;
    dst[o] = hi;
    dst[o + (size_t)H * H] = (f16)lo;
}

// k1: fp32 k-ordered FMA-chain GEMM (BLAS-replica) + fp32-replica LIF -> masks.
// tile 128 b-rows x 256 h-cols, 256 threads = 16 ht x 16 bt, thread = 8b x 16h.
__global__ __launch_bounds__(256, 2) void k1_chain(
    const float* __restrict__ x, const float* __restrict__ w1,
    const float* __restrict__ b1, unsigned short* __restrict__ s1b) {
    __shared__ float xs[32][132];   // [k][b]; stride 132: rows 16B-aligned, banks spread
    __shared__ float ws[32][256];   // [k][h]
    const int hblk = blockIdx.x;    // 4
    const int bblk = blockIdx.y;    // 512
    const int tid = threadIdx.x;
    const int ht = tid & 15, bt = tid >> 4;
    const int h0 = hblk * 256, b0 = bblk * 128;

    float acc[8][16] = {};

    float4 xv[4], wv[8];
#pragma unroll
    for (int i = 0; i < 4; ++i) {
        int idx = tid + 256 * i;            // 1024 f4: 128 rows x 8 segs
        int br = idx >> 3, ks = idx & 7;
        xv[i] = *(const float4*)&x[(size_t)(b0 + br) * IN + ks * 4];
    }
#pragma unroll
    for (int i = 0; i < 8; ++i) {
        int idx = tid + 256 * i;            // 2048 f4: 32 rows x 64 segs
        int kr = idx >> 6, c4 = idx & 63;
        wv[i] = *(const float4*)&w1[(size_t)kr * H + h0 + c4 * 4];
    }

    for (int kc = 0; kc < 512; kc += 32) {
        __syncthreads();                    // prev compute's LDS reads done
#pragma unroll
        for (int i = 0; i < 4; ++i) {
            int idx = tid + 256 * i;
            int br = idx >> 3, ks = idx & 7;
            xs[ks * 4 + 0][br] = xv[i].x;
            xs[ks * 4 + 1][br] = xv[i].y;
            xs[ks * 4 + 2][br] = xv[i].z;
            xs[ks * 4 + 3][br] = xv[i].w;
        }
#pragma unroll
        for (int i = 0; i < 8; ++i) {
            int idx = tid + 256 * i;
            int kr = idx >> 6, c4 = idx & 63;
            *(float4*)&ws[kr][c4 * 4] = wv[i];
        }
        __syncthreads();
        int kn = (kc + 32) & 511;           // wraps to 0 on last chunk (dummy)
#pragma unroll
        for (int i = 0; i < 4; ++i) {
            int idx = tid + 256 * i;
            int br = idx >> 3, ks = idx & 7;
            xv[i] = *(const float4*)&x[(size_t)(b0 + br) * IN + kn + ks * 4];
        }
#pragma unroll
        for (int i = 0; i < 8; ++i) {
            int idx = tid + 256 * i;
            int kr = idx >> 6, c4 = idx & 63;
            wv[i] = *(const float4*)&w1[(size_t)(kn + kr) * H + h0 + c4 * 4];
        }
#pragma unroll 2
        for (int k = 0; k < 32; ++k) {
            float xr[8];
            *(float4*)&xr[0] = *(const float4*)&xs[k][bt * 8];
            *(float4*)&xr[4] = *(const float4*)&xs[k][bt * 8 + 4];
            float wr[16];
#pragma unroll
            for (int g = 0; g < 4; ++g)
                *(float4*)&wr[g * 4] = *(const float4*)&ws[k][ht * 4 + 64 * g];
#pragma unroll
            for (int i = 0; i < 8; ++i)
#pragma unroll
                for (int j = 0; j < 16; ++j)
                    acc[i][j] = fmaf(xr[i], wr[j], acc[i][j]);  // strict k-order chain
        }
    }

    float b1v[16];
#pragma unroll
    for (int g = 0; g < 4; ++g)
#pragma unroll
        for (int m = 0; m < 4; ++m)
            b1v[g * 4 + m] = b1[h0 + g * 64 + ht * 4 + m];
#pragma unroll
    for (int i = 0; i < 8; ++i) {
        unsigned short outb[16];
#pragma unroll
        for (int j = 0; j < 16; ++j) {
            float c = __fadd_rn(acc[i][j], b1v[j]);
            float m = 0.0f;
            unsigned bits = 0u;
#pragma unroll
            for (int t = 0; t < 10; ++t) {
                float rst = (m > 1.0f) ? 1.0f : 0.0f;
                m = __fmul_rn(0.9f, m);
                m = __fadd_rn(m, c);
                m = __fsub_rn(m, rst);
                if (m > 1.0f) bits |= (1u << t);
            }
            outb[j] = (unsigned short)bits;
        }
        size_t row = (size_t)(b0 + bt * 8 + i);
#pragma unroll
        for (int g = 0; g < 4; ++g)
            *(int2*)&s1b[row * H + h0 + g * 64 + ht * 4] = ((const int2*)outb)[g];
    }
}

// k2: spike GEMM. Block = 64 rows x 32 cols, 512 threads = 8 waves:
// wave = (strip = w&3) x (colfrag = w>>2); each wave owns all 10 timesteps of
// its 16 cols. Fragment-linear LDS, BK=64, depth-2 global_load_lds pipeline.
// Epilogue: LIF-2 + ballot -> u16 spike masks (no cross-lane reduce).
__global__ __launch_bounds__(512, 4) void k2_spikes_gemm(
    const unsigned short* __restrict__ s1bits, const f16* __restrict__ w2d,
    const float* __restrict__ b2, u32* __restrict__ po32) {
    // [2 bufs][kch][role][slot] fragment-linear
    __shared__ __align__(16) char ldsraw[32768];
    i32x4 (*AL)[2][4][64]    = (i32x4 (*)[2][4][64])ldsraw;              // 2x8KB
    i32x4 (*BL)[2][2][2][64] = (i32x4 (*)[2][2][2][64])(ldsraw + 16384); // 2x8KB

    const int jblk = blockIdx.x, bblk = blockIdx.y;
    const int tid = threadIdx.x;
    const int lane = tid & 63, wave = tid >> 6;
    const int strip = wave & 3, cfw = wave >> 2;   // compute roles
    const int l15 = lane & 15, loct = lane >> 4;

    // staging roles: waves 0-3 stage A strips, waves 4-7 stage B (plane bp,
    // colfrag bcf). slot == lane -> LDS dest = base + lane*16, exactly
    // global_load_lds semantics; source matches fragment placement.
    const bool stB = (wave >= 4);
    const int bp = (wave >> 1) & 1, bcf = wave & 1;
    const unsigned short* gA =
        s1bits + (size_t)(bblk * 64 + strip * 16 + l15) * 1024 + loct * 8;
    const f16* gB = w2d + (size_t)bp * H * H
                  + (size_t)(jblk * 32 + bcf * 16 + l15) * 1024 + loct * 8;

    f32x4 acc[10][2] = {};   // [tt][plane] = 80 acc regs

    typedef union { i32x4 i; unsigned long long u[2]; f16x8 h; } U;

#define STAGE(t_)                                                        \
    do {                                                                 \
        int bi_ = (t_) & 1;                                              \
        int kk_ = ((t_) * 64) & 1023;                                    \
        if (stB) {                                                       \
            gl_lds16(gB + kk_,      &BL[bi_][0][bp][bcf][0]);            \
            gl_lds16(gB + kk_ + 32, &BL[bi_][1][bp][bcf][0]);            \
        } else {                                                         \
            gl_lds16(gA + kk_,      &AL[bi_][0][strip][0]);              \
            gl_lds16(gA + kk_ + 32, &AL[bi_][1][strip][0]);              \
        }                                                                \
    } while (0)

    // prologue: stage tile 0, release it
    STAGE(0);
    asm volatile("s_waitcnt vmcnt(0)" ::: "memory");
    __builtin_amdgcn_s_barrier();

    for (int t = 0; t < 16; ++t) {
        const int bi = t & 1;
        // stage next tile into buf^1: its readers passed the previous
        // end-of-tile barrier, so the async DMA writes are race-free.
        STAGE(t + 1);   // t=15 wraps to kk=0 (dummy; drained before epilogue)
#pragma unroll
        for (int kch = 0; kch < 2; ++kch) {
            U m;
            m.i = AL[bi][kch][strip][lane];
            U b0v; b0v.i = BL[bi][kch][0][cfw][lane];
            U b1v; b1v.i = BL[bi][kch][1][cfw][lane];
            f16x8 bf0 = b0v.h, bf1 = b1v.h;
            __builtin_amdgcn_s_setprio(1);
#pragma unroll
            for (int tt = 0; tt < 10; ++tt) {
                const int sh = 10 - tt;
                U r;
                r.u[0] = (m.u[0] << sh) & 0x0400040004000400ULL;
                r.u[1] = (m.u[1] << sh) & 0x0400040004000400ULL;
                acc[tt][0] = MFMA16(r.h, bf0, acc[tt][0]);
                acc[tt][1] = MFMA16(r.h, bf1, acc[tt][1]);
            }
            __builtin_amdgcn_s_setprio(0);
        }
        // drain this tile's prefetch DMA, then release buf^1 to all waves.
        asm volatile("s_waitcnt vmcnt(0)" ::: "memory");
        __builtin_amdgcn_s_barrier();
    }
#undef STAGE

    // epilogue: Dekker combine in f64 (kept: guards near-threshold spikes),
    // fp32-replica LIF-2 (ops bit-identical to r9/r14), then __ballot ->
    // u16 col-spike-mask per (tt, row). po32 word [jblk][tt][row]:
    // lo u16 = cfw0 cols 0-15, hi u16 = cfw1 cols 0-15. Each halfword is
    // written exactly once (byte-granular store, no RMW). No barrier needed.
    int col0 = jblk * 32 + cfw * 16 + l15;
    float b2v = b2[col0];
    float m2[4] = {0.0f, 0.0f, 0.0f, 0.0f};
    unsigned short* pw = (unsigned short*)po32;

#pragma unroll
    for (int tt = 0; tt < 10; ++tt) {
#pragma unroll
        for (int r = 0; r < 4; ++r) {
            float iv = (float)((double)acc[tt][0][r] * 16384.0 + (double)acc[tt][1][r] * 8.0);
            iv = __fadd_rn(iv, b2v);
            float rst = (m2[r] > 1.0f) ? 1.0f : 0.0f;
            m2[r] = __fmul_rn(0.9f, m2[r]);
            m2[r] = __fadd_rn(m2[r], iv);
            m2[r] = __fsub_rn(m2[r], rst);
            unsigned long long bal = __ballot(m2[r] > 1.0f);
            if (l15 == r) {
                int row = bblk * 64 + strip * 16 + loct * 4 + r;
                pw[(((size_t)jblk * 10 + tt) * BSZ + row) * 2 + cfw] =
                    (unsigned short)(bal >> (loct * 16));
            }
        }
    }
}

// k3: mask->wo dot in ascending column order + fp32-replica LIF-out, mean.
// Per b-row: 320 coalesced u32 mask loads; per mask 32 predicated f32 adds
// with the wo 32-chunk held in registers (staged via LDS broadcast).
__global__ __launch_bounds__(256) void k3_out(
    const u32* __restrict__ po32, const float* __restrict__ wo,
    const float* __restrict__ bo, float* __restrict__ out) {
    __shared__ float wos[1024];
    const int tid = threadIdx.x;
    for (int i = tid; i < 1024; i += 256) wos[i] = wo[i];
    __syncthreads();
    const int b = blockIdx.x * 256 + tid;

    float inp[10] = {};
    for (int jb = 0; jb < 32; ++jb) {
        float wr[32];
#pragma unroll
        for (int g = 0; g < 8; ++g)
            *(float4*)&wr[g * 4] = *(const float4*)&wos[jb * 32 + g * 4];
#pragma unroll
        for (int t = 0; t < 10; ++t) {
            u32 mk = po32[((size_t)jb * 10 + t) * BSZ + b];
#pragma unroll
            for (int bit = 0; bit < 32; ++bit)
                inp[t] += ((mk >> bit) & 1u) ? wr[bit] : 0.0f;
        }
    }

    float bov = bo[0];
    float mo = 0.0f, s = 0.0f;
#pragma unroll
    for (int t = 0; t < 10; ++t) {
        float iv = __fadd_rn(inp[t], bov);
        float rst = (mo > 1.0f) ? 1.0f : 0.0f;
        mo = __fmul_rn(0.9f, mo);
        mo = __fadd_rn(mo, iv);
        mo = __fsub_rn(mo, rst);
        s += mo;
    }
    out[b] = s / 10.0f;
}

extern "C" void kernel_launch(void* const* d_in, const int* in_sizes, int n_in,
                              void* d_out, int out_size, void* d_ws, size_t ws_size,
                              hipStream_t stream) {
    (void)in_sizes; (void)n_in; (void)out_size; (void)ws_size;
    const float* x  = (const float*)d_in[0];
    const float* W1 = (const float*)d_in[1];
    const float* b1 = (const float*)d_in[2];
    const float* W2 = (const float*)d_in[3];
    const float* b2 = (const float*)d_in[4];
    const float* Wo = (const float*)d_in[5];
    const float* bo = (const float*)d_in[6];
    float* out = (float*)d_out;

    char* ws = (char*)d_ws;
    f16* w2d = (f16*)ws;                                                   // 4 MiB @ 0
    unsigned short* s1bits = (unsigned short*)(ws + ((size_t)16 << 20));   // 128 MiB
    u32* po32 = (u32*)(ws + ((size_t)160 << 20));                          // 80 MiB

    prep_dekker<<<dim3((H * H) / 256), 256, 0, stream>>>(W2, w2d);
    k1_chain<<<dim3(4, BSZ / 128), 256, 0, stream>>>(x, W1, b1, s1bits);
    k2_spikes_gemm<<<dim3(H / 32, BSZ / 64), 512, 0, stream>>>(s1bits, w2d, b2, po32);
    k3_out<<<dim3(BSZ / 256), 256, 0, stream>>>(po32, Wo, bo, out);
}